// Round 1
// baseline (196.275 us; speedup 1.0000x reference)
//
#include <hip/hip_runtime.h>

#define Bn 32
#define Wn 128
#define Sn 192
#define Dn 768
#define Hn 10
#define BHn 30
#define Cn 50
#define CAP 8
#define NEGV -1e30f
#define OCH 14

__device__ __forceinline__ float fsig(float x) {
    return __builtin_amdgcn_rcpf(1.0f + __expf(-x));
}
__device__ __forceinline__ float ftanh(float x) {
    return 1.0f - 2.0f * __builtin_amdgcn_rcpf(1.0f + __expf(2.0f * x));
}

// ---------------- zero counters ----------------
__global__ void k_zero(int* cnt) {
    int i = blockIdx.x * blockDim.x + threadIdx.x;
    if (i < Bn * Wn) cnt[i] = 0;
}

// ---------------- build token->word inverse lists ----------------
__global__ void k_lists(const int* __restrict__ b2t, int* cnt, int* lists) {
    int idx = blockIdx.x * blockDim.x + threadIdx.x;
    if (idx >= Bn * Sn) return;
    int b = idx / Sn;
    int w = b2t[idx];
    if (w < 0 || w >= Wn) return;
    int s = idx % Sn;
    int pos = atomicAdd(&cnt[b * Wn + w], 1);
    if (pos < CAP) lists[(b * Wn + w) * CAP + pos] = s;
}

// ---------------- fused mean(3 layers) + segment-mean ----------------
__global__ __launch_bounds__(192) void k_bertout(const float* __restrict__ hid,
                                                 const int* __restrict__ cnt,
                                                 const int* __restrict__ lists,
                                                 float* __restrict__ bert) {
    int bw = blockIdx.x;  // b*Wn + w
    int d4 = threadIdx.x; // 0..191 (float4 chunks of 768)
    int b = bw / Wn;
    int c = cnt[bw];
    int cc = c < CAP ? c : CAP;
    float4 acc = {0.f, 0.f, 0.f, 0.f};
    for (int tk = 0; tk < cc; ++tk) {
        int s = lists[bw * CAP + tk];
#pragma unroll
        for (int l = 0; l < 3; ++l) {
            const float4* p = (const float4*)(hid + ((size_t)(l * Bn + b) * (Sn + 1) + (s + 1)) * Dn) + d4;
            float4 v = *p;
            acc.x += v.x; acc.y += v.y; acc.z += v.z; acc.w += v.w;
        }
    }
    float inv = 1.0f / (3.0f * (float)(c > 0 ? c : 1));
    acc.x *= inv; acc.y *= inv; acc.z *= inv; acc.w *= inv;
    ((float4*)(bert + (size_t)bw * Dn))[d4] = acc;
}

// ---------------- input-gate projections xg = bert @ Wih^T + bih (both dirs) ----------------
__global__ __launch_bounds__(320) void k_xg(const float* __restrict__ bert,
                                            const float* __restrict__ Wf, const float* __restrict__ bf,
                                            const float* __restrict__ Wb, const float* __restrict__ bb,
                                            float* __restrict__ xg) {
    __shared__ float xl[16 * Dn]; // 48KB: 16 time rows
    int b = blockIdx.x >> 3;
    int tc = blockIdx.x & 7;
    int t0 = tc * 16;
    for (int idx = threadIdx.x; idx < 16 * Dn; idx += 320)
        xl[idx] = bert[(size_t)(b * Wn + t0) * Dn + idx];
    __syncthreads();

    int g = threadIdx.x >> 2;  // 0..79
    int tq = threadIdx.x & 3;  // 0..3 -> 4 time rows each
    int dir = g / 40;
    int row = g % 40;
    const float* wrow = (dir ? Wb : Wf) + row * Dn;
    float bias = (dir ? bb : bf)[row];
    const float* x0 = xl + (tq * 4 + 0) * Dn;
    const float* x1 = xl + (tq * 4 + 1) * Dn;
    const float* x2 = xl + (tq * 4 + 2) * Dn;
    const float* x3 = xl + (tq * 4 + 3) * Dn;
    float a0 = 0.f, a1 = 0.f, a2 = 0.f, a3 = 0.f;
    for (int k = 0; k < Dn; ++k) {
        float wv = wrow[k];
        a0 += wv * x0[k]; a1 += wv * x1[k]; a2 += wv * x2[k]; a3 += wv * x3[k];
    }
    size_t base = (size_t)(dir * Bn + b) * Wn + t0 + tq * 4;
    xg[(base + 0) * 40 + row] = a0 + bias;
    xg[(base + 1) * 40 + row] = a1 + bias;
    xg[(base + 2) * 40 + row] = a2 + bias;
    xg[(base + 3) * 40 + row] = a3 + bias;
}

// ---------------- LSTM scan (dir x 4 batch-groups = 8 blocks) ----------------
__global__ __launch_bounds__(128) void k_lstm(const float* __restrict__ xg,
                                              const float* __restrict__ Whh_f, const float* __restrict__ bhh_f,
                                              const float* __restrict__ Whh_b, const float* __restrict__ bhh_b,
                                              float* __restrict__ hs) {
    int dir = blockIdx.x & 1;
    int bq = blockIdx.x >> 1; // 0..3
    int tid = threadIdx.x;
    bool active = tid < 80;
    int bl = tid / Hn;           // local batch 0..7
    int b = bq * 8 + bl;         // global batch
    int j = tid % Hn;

    const float* Whh = dir ? Whh_b : Whh_f;
    const float* bhh = dir ? bhh_b : bhh_f;
    float wi[Hn], wf[Hn], wg[Hn], wo[Hn];
    float bi = 0.f, bf_ = 0.f, bg = 0.f, bo = 0.f;
    if (active) {
#pragma unroll
        for (int k = 0; k < Hn; ++k) {
            wi[k] = Whh[(0 * Hn + j) * Hn + k];
            wf[k] = Whh[(1 * Hn + j) * Hn + k];
            wg[k] = Whh[(2 * Hn + j) * Hn + k];
            wo[k] = Whh[(3 * Hn + j) * Hn + k];
        }
        bi = bhh[j]; bf_ = bhh[Hn + j]; bg = bhh[2 * Hn + j]; bo = bhh[3 * Hn + j];
    }
    __shared__ float hbuf[2][8 * 11];
    if (active) hbuf[0][bl * 11 + j] = 0.f;
    float c = 0.f;
    __syncthreads();

    for (int step = 0; step < Wn; ++step) {
        int t = dir ? (Wn - 1 - step) : step;
        int cur = step & 1;
        if (active) {
            float hv[Hn];
#pragma unroll
            for (int k = 0; k < Hn; ++k) hv[k] = hbuf[cur][bl * 11 + k];
            const float* xr = xg + ((size_t)(dir * Bn + b) * Wn + t) * 40;
            float gi = xr[j] + bi;
            float gf = xr[Hn + j] + bf_;
            float gg = xr[2 * Hn + j] + bg;
            float go = xr[3 * Hn + j] + bo;
#pragma unroll
            for (int k = 0; k < Hn; ++k) {
                gi += wi[k] * hv[k];
                gf += wf[k] * hv[k];
                gg += wg[k] * hv[k];
                go += wo[k] * hv[k];
            }
            c = fsig(gf) * c + fsig(gi) * ftanh(gg);
            float h = fsig(go) * ftanh(c);
            hs[((size_t)(dir * Bn + b) * Wn + t) * Hn + j] = h;
            hbuf[cur ^ 1][bl * 11 + j] = h;
        }
        __syncthreads();
    }
}

// ---------------- MLP heads: 4x relu(x@W+b) with appended 1 ----------------
__global__ __launch_bounds__(128) void k_mlp(const float* __restrict__ hs,
                                             const float* __restrict__ uW1, const float* __restrict__ ub1,
                                             const float* __restrict__ uW2, const float* __restrict__ ub2,
                                             const float* __restrict__ dW1, const float* __restrict__ db1,
                                             const float* __restrict__ dW2, const float* __restrict__ db2,
                                             float* __restrict__ harr) {
    int bt = blockIdx.x; // b*Wn + t
    int b = bt / Wn, t = bt % Wn;
    __shared__ float x[20];
    int tid = threadIdx.x;
    if (tid < 20) {
        x[tid] = (tid < Hn) ? hs[((size_t)(0 * Bn + b) * Wn + t) * Hn + tid]
                            : hs[((size_t)(1 * Bn + b) * Wn + t) * Hn + (tid - Hn)];
    }
    __syncthreads();
    if (tid >= 124) return;
    int which = tid / 31, k = tid % 31;
    float v;
    if (k == 30) {
        v = 1.0f;
    } else {
        const float* Wm;
        const float* bv;
        if (which == 0) { Wm = uW1; bv = ub1; }
        else if (which == 1) { Wm = uW2; bv = ub2; }
        else if (which == 2) { Wm = dW1; bv = db1; }
        else { Wm = dW2; bv = db2; }
        float a = bv[k];
#pragma unroll
        for (int d = 0; d < 20; ++d) a += x[d] * Wm[d * BHn + k];
        v = a > 0.f ? a : 0.f;
    }
    harr[((size_t)which * Bn * Wn + bt) * 31 + k] = v;
}

// ---------------- unlabeled scores row + softmax + depind CE ----------------
__global__ __launch_bounds__(128) void k_unlab(const float* __restrict__ harr,
                                               const float* __restrict__ U0, const float* __restrict__ ubias,
                                               const int* __restrict__ heads, const unsigned char* __restrict__ masks,
                                               float* __restrict__ un_part) {
    int b = blockIdx.x / (Wn - 1);
    int i = 1 + blockIdx.x % (Wn - 1);
    const float* h1a = harr;                        // un h1
    const float* h2a = harr + (size_t)Bn * Wn * 31; // un h2
    __shared__ float h1row[31], tg[31], red[128];
    __shared__ float h2s[Wn * 31];
    int tid = threadIdx.x;
    for (int idx = tid; idx < Wn * 31; idx += 128)
        h2s[idx] = h2a[(size_t)b * Wn * 31 + idx];
    if (tid < 31) h1row[tid] = h1a[((size_t)b * Wn + i) * 31 + tid];
    __syncthreads();
    if (tid < 31) {
        float a = 0.f;
        for (int h = 0; h < 31; ++h) a += h1row[h] * U0[h * 31 + tid];
        tg[tid] = a;
    }
    __syncthreads();
    float s = ubias[0];
    {
        const float* h2p = h2s + tid * 31;
#pragma unroll
        for (int g = 0; g < 31; ++g) s += tg[g] * h2p[g];
    }
    if (tid == i) s = NEGV;
    red[tid] = s;
    __syncthreads();
    for (int off = 64; off > 0; off >>= 1) {
        if (tid < off) red[tid] = fmaxf(red[tid], red[tid + off]);
        __syncthreads();
    }
    float m = red[0];
    __syncthreads();
    red[tid] = __expf(s - m);
    __syncthreads();
    for (int off = 64; off > 0; off >>= 1) {
        if (tid < off) red[tid] += red[tid + off];
        __syncthreads();
    }
    float lse = m + __logf(red[0]);
    int head = heads[b * Wn + i];
    if (masks[b * Wn + i]) head = -1;
    if (head >= 0 && head < Wn) {
        if (tid == head) un_part[blockIdx.x] = -(s - lse);
    } else {
        if (tid == 0) un_part[blockIdx.x] = 0.f;
    }
}

// ---------------- deprel scores at j=head only + CE ----------------
__global__ __launch_bounds__(256) void k_deprel(const float* __restrict__ harr,
                                                const float* __restrict__ U, const float* __restrict__ dbias,
                                                const int* __restrict__ heads, const int* __restrict__ dep_rels,
                                                float* __restrict__ dr_part) {
    int b = blockIdx.x >> 3;
    int ic = blockIdx.x & 7;
    const float* h1a = harr + (size_t)2 * Bn * Wn * 31; // dr h1
    const float* h2a = harr + (size_t)3 * Bn * Wn * 31; // dr h2
    __shared__ float Ulds[OCH * 961];
    __shared__ float h1r[16 * 31], h2r[16 * 31], sc[16 * Cn];
    __shared__ int jh[16];
    __shared__ float part[16];
    int tid = threadIdx.x;
    if (tid < 16) {
        int i = ic * 16 + tid;
        int hh = heads[b * Wn + i];
        jh[tid] = (hh >= 0 && hh < Wn) ? hh : 0;
    }
    __syncthreads();
    for (int idx = tid; idx < 16 * 31; idx += 256) {
        int il = idx / 31, k = idx % 31;
        h1r[idx] = h1a[((size_t)b * Wn + ic * 16 + il) * 31 + k];
        h2r[idx] = h2a[((size_t)b * Wn + jh[il]) * 31 + k];
    }
    __syncthreads();
    for (int o0 = 0; o0 < Cn; o0 += OCH) {
        int No = (Cn - o0) < OCH ? (Cn - o0) : OCH;
        for (int idx = tid; idx < No * 961; idx += 256)
            Ulds[idx] = U[(size_t)o0 * 961 + idx];
        __syncthreads();
        int items = 16 * No;
        for (int w = tid; w < items; w += 256) {
            int il = w / No, ol = w % No;
            float h2reg[31];
#pragma unroll
            for (int g = 0; g < 31; ++g) h2reg[g] = h2r[il * 31 + g];
            float acc = 0.f;
            const float* up = Ulds + ol * 961;
            for (int h = 0; h < 31; ++h) {
                float a = h1r[il * 31 + h];
                float tsum = 0.f;
#pragma unroll
                for (int g = 0; g < 31; ++g) tsum += up[h * 31 + g] * h2reg[g];
                acc += a * tsum;
            }
            sc[il * Cn + o0 + ol] = acc + dbias[o0 + ol];
        }
        __syncthreads();
    }
    if (tid < 16) {
        int il = tid;
        int i = ic * 16 + il;
        int r = dep_rels[b * Wn + i];
        float contrib = 0.f;
        if (r != 0 && r > 0 && r < Cn) {
            float m = sc[il * Cn];
            for (int o = 1; o < Cn; ++o) m = fmaxf(m, sc[il * Cn + o]);
            float ssum = 0.f;
            for (int o = 0; o < Cn; ++o) ssum += __expf(sc[il * Cn + o] - m);
            float lse = m + __logf(ssum);
            contrib = -(sc[il * Cn + r] - lse);
        }
        part[il] = contrib;
    }
    __syncthreads();
    if (tid == 0) {
        float a = 0.f;
        for (int k = 0; k < 16; ++k) a += part[k];
        dr_part[blockIdx.x] = a;
    }
}

// ---------------- final reduce ----------------
__global__ __launch_bounds__(256) void k_final(const float* __restrict__ un_part,
                                               const float* __restrict__ dr_part,
                                               float* __restrict__ out) {
    __shared__ float red[256];
    int tid = threadIdx.x;
    float a = 0.f;
    for (int idx = tid; idx < Bn * (Wn - 1); idx += 256) a += un_part[idx];
    if (tid < 256) {
        if (tid < Bn * 8) a += dr_part[tid];
    }
    red[tid] = a;
    __syncthreads();
    for (int off = 128; off > 0; off >>= 1) {
        if (tid < off) red[tid] += red[tid + off];
        __syncthreads();
    }
    if (tid == 0) out[0] = red[0];
}

extern "C" void kernel_launch(void* const* d_in, const int* in_sizes, int n_in,
                              void* d_out, int out_size, void* d_ws, size_t ws_size,
                              hipStream_t stream) {
    const float* hiddens = (const float*)d_in[0];
    const int* b2t = (const int*)d_in[1];
    const int* heads = (const int*)d_in[2];
    const int* dep_rels = (const int*)d_in[3];
    const unsigned char* masks = (const unsigned char*)d_in[4];
    // d_in[5] = sent_lens (unused)
    const float* Wih_f = (const float*)d_in[6];
    const float* Whh_f = (const float*)d_in[7];
    const float* bih_f = (const float*)d_in[8];
    const float* bhh_f = (const float*)d_in[9];
    const float* Wih_b = (const float*)d_in[10];
    const float* Whh_b = (const float*)d_in[11];
    const float* bih_b = (const float*)d_in[12];
    const float* bhh_b = (const float*)d_in[13];
    const float* un_W1 = (const float*)d_in[14];
    const float* un_b1 = (const float*)d_in[15];
    const float* un_W2 = (const float*)d_in[16];
    const float* un_b2 = (const float*)d_in[17];
    const float* un_U  = (const float*)d_in[18];
    const float* un_bias = (const float*)d_in[19];
    const float* dr_W1 = (const float*)d_in[20];
    const float* dr_b1 = (const float*)d_in[21];
    const float* dr_W2 = (const float*)d_in[22];
    const float* dr_b2 = (const float*)d_in[23];
    const float* dr_U  = (const float*)d_in[24];
    const float* dr_bias = (const float*)d_in[25];

    char* p = (char*)d_ws;
    float* un_part = (float*)p; p += (size_t)4096 * 4;
    float* dr_part = (float*)p; p += (size_t)256 * 4;
    int* cnt = (int*)p;        p += (size_t)Bn * Wn * 4;
    int* lists = (int*)p;      p += (size_t)Bn * Wn * CAP * 4;
    float* bert = (float*)p;   p += (size_t)Bn * Wn * Dn * 4;
    float* xg = (float*)p;     p += (size_t)2 * Bn * Wn * 40 * 4;
    float* hs = (float*)p;     p += (size_t)2 * Bn * Wn * Hn * 4;
    float* harr = (float*)p;   p += (size_t)4 * Bn * Wn * 31 * 4;

    k_zero<<<(Bn * Wn + 255) / 256, 256, 0, stream>>>(cnt);
    k_lists<<<(Bn * Sn + 255) / 256, 256, 0, stream>>>(b2t, cnt, lists);
    k_bertout<<<Bn * Wn, 192, 0, stream>>>(hiddens, cnt, lists, bert);
    k_xg<<<Bn * 8, 320, 0, stream>>>(bert, Wih_f, bih_f, Wih_b, bih_b, xg);
    k_lstm<<<8, 128, 0, stream>>>(xg, Whh_f, bhh_f, Whh_b, bhh_b, hs);
    k_mlp<<<Bn * Wn, 128, 0, stream>>>(hs, un_W1, un_b1, un_W2, un_b2,
                                       dr_W1, dr_b1, dr_W2, dr_b2, harr);
    k_unlab<<<Bn * (Wn - 1), 128, 0, stream>>>(harr, un_U, un_bias, heads, masks, un_part);
    k_deprel<<<Bn * 8, 256, 0, stream>>>(harr, dr_U, dr_bias, heads, dep_rels, dr_part);
    k_final<<<1, 256, 0, stream>>>(un_part, dr_part, (float*)d_out);
}

// Round 2
// 159.049 us; speedup vs baseline: 1.2341x; 1.2341x over previous
//
#include <hip/hip_runtime.h>

#define Bn 32
#define Wn 128
#define Sn 192
#define Dn 768
#define Hn 10
#define BHn 30
#define Cn 50
#define CAP 8
#define NEGV -1e30f
#define OCH 14
#define XPAD 4

__device__ __forceinline__ float fsig(float x) {
    return __builtin_amdgcn_rcpf(1.0f + __expf(-x));
}
__device__ __forceinline__ float ftanh(float x) {
    return 1.0f - 2.0f * __builtin_amdgcn_rcpf(1.0f + __expf(2.0f * x));
}

// ---------------- zero counters ----------------
__global__ void k_zero(int* cnt) {
    int i = blockIdx.x * blockDim.x + threadIdx.x;
    if (i < Bn * Wn) cnt[i] = 0;
}

// ---------------- build token->word inverse lists ----------------
__global__ void k_lists(const int* __restrict__ b2t, int* cnt, int* lists) {
    int idx = blockIdx.x * blockDim.x + threadIdx.x;
    if (idx >= Bn * Sn) return;
    int b = idx / Sn;
    int w = b2t[idx];
    if (w < 0 || w >= Wn) return;
    int s = idx % Sn;
    int pos = atomicAdd(&cnt[b * Wn + w], 1);
    if (pos < CAP) lists[(b * Wn + w) * CAP + pos] = s;
}

// ---------------- fused mean(3 layers) + segment-mean ----------------
__global__ __launch_bounds__(192) void k_bertout(const float* __restrict__ hid,
                                                 const int* __restrict__ cnt,
                                                 const int* __restrict__ lists,
                                                 float* __restrict__ bert) {
    int bw = blockIdx.x;  // b*Wn + w
    int d4 = threadIdx.x; // 0..191 (float4 chunks of 768)
    int b = bw / Wn;
    int c = cnt[bw];
    int cc = c < CAP ? c : CAP;
    float4 acc = {0.f, 0.f, 0.f, 0.f};
    for (int tk = 0; tk < cc; ++tk) {
        int s = lists[bw * CAP + tk];
#pragma unroll
        for (int l = 0; l < 3; ++l) {
            const float4* p = (const float4*)(hid + ((size_t)(l * Bn + b) * (Sn + 1) + (s + 1)) * Dn) + d4;
            float4 v = *p;
            acc.x += v.x; acc.y += v.y; acc.z += v.z; acc.w += v.w;
        }
    }
    float inv = 1.0f / (3.0f * (float)(c > 0 ? c : 1));
    acc.x *= inv; acc.y *= inv; acc.z *= inv; acc.w *= inv;
    ((float4*)(bert + (size_t)bw * Dn))[d4] = acc;
}

// ---------------- input-gate projections xg = bert @ Wih^T + bih (both dirs) ----------------
__global__ __launch_bounds__(320) void k_xg(const float* __restrict__ bert,
                                            const float* __restrict__ Wf, const float* __restrict__ bf,
                                            const float* __restrict__ Wb, const float* __restrict__ bb,
                                            float* __restrict__ xg) {
    __shared__ float xl[16 * (Dn + XPAD)]; // padded rows to break bank aliasing
    int b = blockIdx.x >> 3;
    int tc = blockIdx.x & 7;
    int t0 = tc * 16;
    // staged float4 copy, row by row (rows padded in LDS)
    for (int idx = threadIdx.x; idx < 16 * (Dn / 4); idx += 320) {
        int r = idx / (Dn / 4), k4 = idx % (Dn / 4);
        float4 v = ((const float4*)(bert + (size_t)(b * Wn + t0 + r) * Dn))[k4];
        ((float4*)(xl + r * (Dn + XPAD)))[k4] = v;
    }
    __syncthreads();

    int g = threadIdx.x >> 2;  // 0..79
    int tq = threadIdx.x & 3;  // 0..3 -> 4 time rows each
    int dir = g / 40;
    int row = g % 40;
    const float4* wrow = (const float4*)((dir ? Wb : Wf) + row * Dn);
    float bias = (dir ? bb : bf)[row];
    const float4* x0 = (const float4*)(xl + (tq * 4 + 0) * (Dn + XPAD));
    const float4* x1 = (const float4*)(xl + (tq * 4 + 1) * (Dn + XPAD));
    const float4* x2 = (const float4*)(xl + (tq * 4 + 2) * (Dn + XPAD));
    const float4* x3 = (const float4*)(xl + (tq * 4 + 3) * (Dn + XPAD));
    float a0 = 0.f, a1 = 0.f, a2 = 0.f, a3 = 0.f;
    for (int k = 0; k < Dn / 4; ++k) {
        float4 w = wrow[k];
        float4 v0 = x0[k], v1 = x1[k], v2 = x2[k], v3 = x3[k];
        a0 += w.x * v0.x + w.y * v0.y + w.z * v0.z + w.w * v0.w;
        a1 += w.x * v1.x + w.y * v1.y + w.z * v1.z + w.w * v1.w;
        a2 += w.x * v2.x + w.y * v2.y + w.z * v2.z + w.w * v2.w;
        a3 += w.x * v3.x + w.y * v3.y + w.z * v3.z + w.w * v3.w;
    }
    size_t base = (size_t)(dir * Bn + b) * Wn + t0 + tq * 4;
    xg[(base + 0) * 40 + row] = a0 + bias;
    xg[(base + 1) * 40 + row] = a1 + bias;
    xg[(base + 2) * 40 + row] = a2 + bias;
    xg[(base + 3) * 40 + row] = a3 + bias;
}

// ---------------- LSTM scan: wave-local, shuffle-based, prefetched ----------------
// 64 sequences (dir x batch); 16 lanes per sequence; 4 sequences per wave.
// 16 blocks x 64 threads; dir uniform per block (blocks 0-7 fwd, 8-15 bwd).
__global__ __launch_bounds__(64) void k_lstm(const float* __restrict__ xg,
                                             const float* __restrict__ Whh_f, const float* __restrict__ bhh_f,
                                             const float* __restrict__ Whh_b, const float* __restrict__ bhh_b,
                                             float* __restrict__ hs) {
    int lane = threadIdx.x;    // 0..63
    int grp = lane >> 4;       // 0..3
    int j = lane & 15;
    int jj = j < Hn ? j : (Hn - 1); // clamp lanes 10..15 (compute duplicates, never store)
    int seq = blockIdx.x * 4 + grp; // 0..63
    int dir = seq >> 5;             // uniform per block
    int b = seq & 31;

    const float* Whh = dir ? Whh_b : Whh_f;
    const float* bhh = dir ? bhh_b : bhh_f;
    float wi[Hn], wf[Hn], wg[Hn], wo[Hn];
#pragma unroll
    for (int k = 0; k < Hn; ++k) {
        wi[k] = Whh[(0 * Hn + jj) * Hn + k];
        wf[k] = Whh[(1 * Hn + jj) * Hn + k];
        wg[k] = Whh[(2 * Hn + jj) * Hn + k];
        wo[k] = Whh[(3 * Hn + jj) * Hn + k];
    }
    float bi = bhh[jj], bf_ = bhh[Hn + jj], bg = bhh[2 * Hn + jj], bo = bhh[3 * Hn + jj];

    const float* xbase = xg + (size_t)(dir * Bn + b) * Wn * 40;
    float* hbase = hs + (size_t)(dir * Bn + b) * Wn * Hn;

    float h = 0.f, c = 0.f;
    int dt = dir ? -1 : 1;
    int t = dir ? (Wn - 1) : 0;
    const float* xr0 = xbase + t * 40;
    float xi = xr0[jj], xf = xr0[Hn + jj], xgg = xr0[2 * Hn + jj], xo = xr0[3 * Hn + jj];

    for (int step = 0; step < Wn; ++step) {
        int tn = t + dt;
        float nxi = 0.f, nxf = 0.f, nxg = 0.f, nxo = 0.f;
        if (step + 1 < Wn) { // prefetch next step's gates (independent of h)
            const float* xrn = xbase + tn * 40;
            nxi = xrn[jj]; nxf = xrn[Hn + jj]; nxg = xrn[2 * Hn + jj]; nxo = xrn[3 * Hn + jj];
        }
        float hv[Hn];
#pragma unroll
        for (int k = 0; k < Hn; ++k) hv[k] = __shfl(h, k, 16);
        float gi = xi + bi, gf = xf + bf_, gg = xgg + bg, go = xo + bo;
#pragma unroll
        for (int k = 0; k < Hn; ++k) {
            gi += wi[k] * hv[k];
            gf += wf[k] * hv[k];
            gg += wg[k] * hv[k];
            go += wo[k] * hv[k];
        }
        c = fsig(gf) * c + fsig(gi) * ftanh(gg);
        h = fsig(go) * ftanh(c);
        if (j < Hn) hbase[t * Hn + j] = h;
        xi = nxi; xf = nxf; xgg = nxg; xo = nxo;
        t = tn;
    }
}

// ---------------- MLP heads: 4x relu(x@W+b) with appended 1 ----------------
__global__ __launch_bounds__(128) void k_mlp(const float* __restrict__ hs,
                                             const float* __restrict__ uW1, const float* __restrict__ ub1,
                                             const float* __restrict__ uW2, const float* __restrict__ ub2,
                                             const float* __restrict__ dW1, const float* __restrict__ db1,
                                             const float* __restrict__ dW2, const float* __restrict__ db2,
                                             float* __restrict__ harr) {
    int bt = blockIdx.x; // b*Wn + t
    int b = bt / Wn, t = bt % Wn;
    __shared__ float x[20];
    int tid = threadIdx.x;
    if (tid < 20) {
        x[tid] = (tid < Hn) ? hs[((size_t)(0 * Bn + b) * Wn + t) * Hn + tid]
                            : hs[((size_t)(1 * Bn + b) * Wn + t) * Hn + (tid - Hn)];
    }
    __syncthreads();
    if (tid >= 124) return;
    int which = tid / 31, k = tid % 31;
    float v;
    if (k == 30) {
        v = 1.0f;
    } else {
        const float* Wm;
        const float* bv;
        if (which == 0) { Wm = uW1; bv = ub1; }
        else if (which == 1) { Wm = uW2; bv = ub2; }
        else if (which == 2) { Wm = dW1; bv = db1; }
        else { Wm = dW2; bv = db2; }
        float a = bv[k];
#pragma unroll
        for (int d = 0; d < 20; ++d) a += x[d] * Wm[d * BHn + k];
        v = a > 0.f ? a : 0.f;
    }
    harr[((size_t)which * Bn * Wn + bt) * 31 + k] = v;
}

// ---------------- unlabeled scores row + softmax + depind CE ----------------
__global__ __launch_bounds__(128) void k_unlab(const float* __restrict__ harr,
                                               const float* __restrict__ U0, const float* __restrict__ ubias,
                                               const int* __restrict__ heads, const unsigned char* __restrict__ masks,
                                               float* __restrict__ un_part) {
    int b = blockIdx.x / (Wn - 1);
    int i = 1 + blockIdx.x % (Wn - 1);
    const float* h1a = harr;                        // un h1
    const float* h2a = harr + (size_t)Bn * Wn * 31; // un h2
    __shared__ float h1row[31], tg[31], red[128];
    __shared__ float h2s[Wn * 31];
    int tid = threadIdx.x;
    for (int idx = tid; idx < Wn * 31; idx += 128)
        h2s[idx] = h2a[(size_t)b * Wn * 31 + idx];
    if (tid < 31) h1row[tid] = h1a[((size_t)b * Wn + i) * 31 + tid];
    __syncthreads();
    if (tid < 31) {
        float a = 0.f;
        for (int h = 0; h < 31; ++h) a += h1row[h] * U0[h * 31 + tid];
        tg[tid] = a;
    }
    __syncthreads();
    float s = ubias[0];
    {
        const float* h2p = h2s + tid * 31;
#pragma unroll
        for (int g = 0; g < 31; ++g) s += tg[g] * h2p[g];
    }
    if (tid == i) s = NEGV;
    red[tid] = s;
    __syncthreads();
    for (int off = 64; off > 0; off >>= 1) {
        if (tid < off) red[tid] = fmaxf(red[tid], red[tid + off]);
        __syncthreads();
    }
    float m = red[0];
    __syncthreads();
    red[tid] = __expf(s - m);
    __syncthreads();
    for (int off = 64; off > 0; off >>= 1) {
        if (tid < off) red[tid] += red[tid + off];
        __syncthreads();
    }
    float lse = m + __logf(red[0]);
    int head = heads[b * Wn + i];
    if (masks[b * Wn + i]) head = -1;
    if (head >= 0 && head < Wn) {
        if (tid == head) un_part[blockIdx.x] = -(s - lse);
    } else {
        if (tid == 0) un_part[blockIdx.x] = 0.f;
    }
}

// ---------------- deprel scores at j=head only + CE ----------------
__global__ __launch_bounds__(256) void k_deprel(const float* __restrict__ harr,
                                                const float* __restrict__ U, const float* __restrict__ dbias,
                                                const int* __restrict__ heads, const int* __restrict__ dep_rels,
                                                float* __restrict__ dr_part) {
    int b = blockIdx.x >> 3;
    int ic = blockIdx.x & 7;
    const float* h1a = harr + (size_t)2 * Bn * Wn * 31; // dr h1
    const float* h2a = harr + (size_t)3 * Bn * Wn * 31; // dr h2
    __shared__ float Ulds[OCH * 961];
    __shared__ float h1r[16 * 31], h2r[16 * 31], sc[16 * Cn];
    __shared__ int jh[16];
    __shared__ float part[16];
    int tid = threadIdx.x;
    if (tid < 16) {
        int i = ic * 16 + tid;
        int hh = heads[b * Wn + i];
        jh[tid] = (hh >= 0 && hh < Wn) ? hh : 0;
    }
    __syncthreads();
    for (int idx = tid; idx < 16 * 31; idx += 256) {
        int il = idx / 31, k = idx % 31;
        h1r[idx] = h1a[((size_t)b * Wn + ic * 16 + il) * 31 + k];
        h2r[idx] = h2a[((size_t)b * Wn + jh[il]) * 31 + k];
    }
    __syncthreads();
    for (int o0 = 0; o0 < Cn; o0 += OCH) {
        int No = (Cn - o0) < OCH ? (Cn - o0) : OCH;
        for (int idx = tid; idx < No * 961; idx += 256)
            Ulds[idx] = U[(size_t)o0 * 961 + idx];
        __syncthreads();
        int items = 16 * No;
        for (int w = tid; w < items; w += 256) {
            int il = w / No, ol = w % No;
            float h2reg[31];
#pragma unroll
            for (int g = 0; g < 31; ++g) h2reg[g] = h2r[il * 31 + g];
            float acc = 0.f;
            const float* up = Ulds + ol * 961;
            for (int h = 0; h < 31; ++h) {
                float a = h1r[il * 31 + h];
                float tsum = 0.f;
#pragma unroll
                for (int g = 0; g < 31; ++g) tsum += up[h * 31 + g] * h2reg[g];
                acc += a * tsum;
            }
            sc[il * Cn + o0 + ol] = acc + dbias[o0 + ol];
        }
        __syncthreads();
    }
    if (tid < 16) {
        int il = tid;
        int i = ic * 16 + il;
        int r = dep_rels[b * Wn + i];
        float contrib = 0.f;
        if (r != 0 && r > 0 && r < Cn) {
            float m = sc[il * Cn];
            for (int o = 1; o < Cn; ++o) m = fmaxf(m, sc[il * Cn + o]);
            float ssum = 0.f;
            for (int o = 0; o < Cn; ++o) ssum += __expf(sc[il * Cn + o] - m);
            float lse = m + __logf(ssum);
            contrib = -(sc[il * Cn + r] - lse);
        }
        part[il] = contrib;
    }
    __syncthreads();
    if (tid == 0) {
        float a = 0.f;
        for (int k = 0; k < 16; ++k) a += part[k];
        dr_part[blockIdx.x] = a;
    }
}

// ---------------- final reduce ----------------
__global__ __launch_bounds__(256) void k_final(const float* __restrict__ un_part,
                                               const float* __restrict__ dr_part,
                                               float* __restrict__ out) {
    __shared__ float red[256];
    int tid = threadIdx.x;
    float a = 0.f;
    for (int idx = tid; idx < Bn * (Wn - 1); idx += 256) a += un_part[idx];
    if (tid < 256) {
        if (tid < Bn * 8) a += dr_part[tid];
    }
    red[tid] = a;
    __syncthreads();
    for (int off = 128; off > 0; off >>= 1) {
        if (tid < off) red[tid] += red[tid + off];
        __syncthreads();
    }
    if (tid == 0) out[0] = red[0];
}

extern "C" void kernel_launch(void* const* d_in, const int* in_sizes, int n_in,
                              void* d_out, int out_size, void* d_ws, size_t ws_size,
                              hipStream_t stream) {
    const float* hiddens = (const float*)d_in[0];
    const int* b2t = (const int*)d_in[1];
    const int* heads = (const int*)d_in[2];
    const int* dep_rels = (const int*)d_in[3];
    const unsigned char* masks = (const unsigned char*)d_in[4];
    // d_in[5] = sent_lens (unused)
    const float* Wih_f = (const float*)d_in[6];
    const float* Whh_f = (const float*)d_in[7];
    const float* bih_f = (const float*)d_in[8];
    const float* bhh_f = (const float*)d_in[9];
    const float* Wih_b = (const float*)d_in[10];
    const float* Whh_b = (const float*)d_in[11];
    const float* bih_b = (const float*)d_in[12];
    const float* bhh_b = (const float*)d_in[13];
    const float* un_W1 = (const float*)d_in[14];
    const float* un_b1 = (const float*)d_in[15];
    const float* un_W2 = (const float*)d_in[16];
    const float* un_b2 = (const float*)d_in[17];
    const float* un_U  = (const float*)d_in[18];
    const float* un_bias = (const float*)d_in[19];
    const float* dr_W1 = (const float*)d_in[20];
    const float* dr_b1 = (const float*)d_in[21];
    const float* dr_W2 = (const float*)d_in[22];
    const float* dr_b2 = (const float*)d_in[23];
    const float* dr_U  = (const float*)d_in[24];
    const float* dr_bias = (const float*)d_in[25];

    char* p = (char*)d_ws;
    float* un_part = (float*)p; p += (size_t)4096 * 4;
    float* dr_part = (float*)p; p += (size_t)256 * 4;
    int* cnt = (int*)p;        p += (size_t)Bn * Wn * 4;
    int* lists = (int*)p;      p += (size_t)Bn * Wn * CAP * 4;
    float* bert = (float*)p;   p += (size_t)Bn * Wn * Dn * 4;
    float* xg = (float*)p;     p += (size_t)2 * Bn * Wn * 40 * 4;
    float* hs = (float*)p;     p += (size_t)2 * Bn * Wn * Hn * 4;
    float* harr = (float*)p;   p += (size_t)4 * Bn * Wn * 31 * 4;

    k_zero<<<(Bn * Wn + 255) / 256, 256, 0, stream>>>(cnt);
    k_lists<<<(Bn * Sn + 255) / 256, 256, 0, stream>>>(b2t, cnt, lists);
    k_bertout<<<Bn * Wn, 192, 0, stream>>>(hiddens, cnt, lists, bert);
    k_xg<<<Bn * 8, 320, 0, stream>>>(bert, Wih_f, bih_f, Wih_b, bih_b, xg);
    k_lstm<<<16, 64, 0, stream>>>(xg, Whh_f, bhh_f, Whh_b, bhh_b, hs);
    k_mlp<<<Bn * Wn, 128, 0, stream>>>(hs, un_W1, un_b1, un_W2, un_b2,
                                       dr_W1, dr_b1, dr_W2, dr_b2, harr);
    k_unlab<<<Bn * (Wn - 1), 128, 0, stream>>>(harr, un_U, un_bias, heads, masks, un_part);
    k_deprel<<<Bn * 8, 256, 0, stream>>>(harr, dr_U, dr_bias, heads, dep_rels, dr_part);
    k_final<<<1, 256, 0, stream>>>(un_part, dr_part, (float*)d_out);
}